// Round 1
// baseline (2242.533 us; speedup 1.0000x reference)
//
#include <hip/hip_runtime.h>

#define B 64
#define T 256
#define C 384
#define H 6
#define HS 64
#define DFF 1536
#define BT (B*T)

// ---------------- LayerNorm: one wave per token ----------------
__global__ __launch_bounds__(64) void ln_kernel(const float* __restrict__ x,
    const float* __restrict__ g, const float* __restrict__ bta,
    float* __restrict__ out) {
  int t = blockIdx.x;
  int lane = threadIdx.x;
  const float* row = x + (size_t)t * C;
  float v[6];
  float s = 0.f, ss = 0.f;
  #pragma unroll
  for (int i = 0; i < 6; ++i) {
    v[i] = row[lane + i * 64];
    s += v[i];
    ss += v[i] * v[i];
  }
  #pragma unroll
  for (int m = 32; m >= 1; m >>= 1) {
    s += __shfl_xor(s, m);
    ss += __shfl_xor(ss, m);
  }
  float mu = s / C;
  float var = ss / C - mu * mu;
  float rstd = rsqrtf(var + 1e-5f);
  float* orow = out + (size_t)t * C;
  #pragma unroll
  for (int i = 0; i < 6; ++i) {
    int c = lane + i * 64;
    orow[c] = (v[i] - mu) * rstd * g[c] + bta[c];
  }
}

// ---------------- QKV projection: block = (b,h, 32-token tile) ----------------
__global__ __launch_bounds__(256) void qkv_kernel(const float* __restrict__ hbuf,
    const float* __restrict__ Wq, const float* __restrict__ Wk,
    const float* __restrict__ Wv,
    float* __restrict__ q, float* __restrict__ k, float* __restrict__ v) {
  __shared__ float hs[32][C];
  int bh = blockIdx.x;  // b*H + h
  int b = bh / H, hh = bh % H;
  int qbase = blockIdx.y * 32;
  int tid = threadIdx.x;
  for (int idx = tid; idx < 32 * C; idx += 256) {
    int r = idx / C, c = idx % C;
    hs[r][c] = hbuf[((size_t)(b * T + qbase + r)) * C + c];
  }
  __syncthreads();
  int kk = tid % 64, quarter = tid / 64;
  const float* Ws[3] = {Wq, Wk, Wv};
  float* outs[3] = {q, k, v};
  #pragma unroll
  for (int m = 0; m < 3; ++m) {
    const float* W = Ws[m] + ((size_t)hh * C) * HS + kk;
    float acc[8];
    #pragma unroll
    for (int r = 0; r < 8; ++r) acc[r] = 0.f;
    for (int c = 0; c < C; ++c) {
      float w = W[(size_t)c * HS];
      #pragma unroll
      for (int r = 0; r < 8; ++r) acc[r] += hs[quarter * 8 + r][c] * w;
    }
    float* o = outs[m];
    #pragma unroll
    for (int r = 0; r < 8; ++r) {
      int t = qbase + quarter * 8 + r;
      o[(((size_t)bh) * T + t) * HS + kk] = acc[r];
    }
  }
}

// ------- attention: block = (b,h, 32-query tile); scores in LDS -------
__global__ __launch_bounds__(256) void attn_kernel(const float* __restrict__ q,
    const float* __restrict__ k, const float* __restrict__ v,
    float* __restrict__ attn) {
  __shared__ float sc[32][T + 1];      // scores, padded
  __shared__ float tile[64][HS + 1];   // K then V tiles
  __shared__ float qs[32][HS + 1];
  int bh = blockIdx.x;
  int b = bh / H, hh = bh % H;
  int qbase = blockIdx.y * 32;
  int tid = threadIdx.x;
  const float scale = 0.125f;  // 1/sqrt(64)
  const float* qptr = q + ((size_t)bh * T) * HS;
  const float* kptr = k + ((size_t)bh * T) * HS;
  const float* vptr = v + ((size_t)bh * T) * HS;
  for (int idx = tid; idx < 32 * HS; idx += 256) {
    int r = idx / HS, c = idx % HS;
    qs[r][c] = qptr[(size_t)(qbase + r) * HS + c];
  }
  int smax = qbase + 32;  // exclusive bound on needed s
  // phase 1: scores
  for (int st = 0; st < smax; st += 64) {
    for (int idx = tid; idx < 64 * HS; idx += 256) {
      int r = idx / HS, c = idx % HS;
      tile[r][c] = kptr[(size_t)(st + r) * HS + c];
    }
    __syncthreads();
    #pragma unroll
    for (int i = 0; i < 8; ++i) {
      int idx = i * 256 + tid;
      int ql = idx / 64, s = idx % 64;
      int tq = qbase + ql;
      int sg = st + s;
      float d;
      if (sg > tq) {
        d = -1e30f;
      } else {
        d = 0.f;
        #pragma unroll
        for (int c = 0; c < HS; ++c) d += qs[ql][c] * tile[s][c];
        d *= scale;
      }
      sc[ql][sg] = d;
    }
    __syncthreads();
  }
  // phase 2: per-row softmax (threads 0..31)
  if (tid < 32) {
    int ql = tid, tq = qbase + ql;
    float m = -1e30f;
    for (int s = 0; s <= tq; ++s) m = fmaxf(m, sc[ql][s]);
    float l = 0.f;
    for (int s = 0; s <= tq; ++s) {
      float e = __expf(sc[ql][s] - m);
      sc[ql][s] = e;
      l += e;
    }
    float inv = 1.f / l;
    for (int s = 0; s <= tq; ++s) sc[ql][s] *= inv;
    for (int s = tq + 1; s < T; ++s) sc[ql][s] = 0.f;
  }
  __syncthreads();
  // phase 3: out = w @ V
  float acc[8];
  #pragma unroll
  for (int i = 0; i < 8; ++i) acc[i] = 0.f;
  for (int st = 0; st < smax; st += 64) {
    for (int idx = tid; idx < 64 * HS; idx += 256) {
      int r = idx / HS, c = idx % HS;
      tile[r][c] = vptr[(size_t)(st + r) * HS + c];
    }
    __syncthreads();
    #pragma unroll
    for (int i = 0; i < 8; ++i) {
      int idx = i * 256 + tid;
      int ql = idx / 64, kk = idx % 64;
      float a = acc[i];
      #pragma unroll
      for (int s = 0; s < 64; ++s) a += sc[ql][st + s] * tile[s][kk];
      acc[i] = a;
    }
    __syncthreads();
  }
  #pragma unroll
  for (int i = 0; i < 8; ++i) {
    int idx = i * 256 + tid;
    int ql = idx / 64, kk = idx % 64;
    int t = qbase + ql;
    attn[(((size_t)(b * T + t)) * H + hh) * HS + kk] = acc[i];
  }
}

// ------- output projection + residual: x2 = x + attn@Wo + bo -------
__global__ __launch_bounds__(384) void proj_kernel(const float* __restrict__ attn,
    const float* __restrict__ Wo, const float* __restrict__ bo,
    const float* __restrict__ x, float* __restrict__ x2) {
  __shared__ float as[32][C];
  int rbase = blockIdx.x * 32;
  int tid = threadIdx.x;  // output col
  for (int idx = tid; idx < 32 * C; idx += 384) {
    int r = idx / C, c = idx % C;
    as[r][c] = attn[(size_t)(rbase + r) * C + c];
  }
  __syncthreads();
  float acc[32];
  #pragma unroll
  for (int r = 0; r < 32; ++r) acc[r] = 0.f;
  for (int c2 = 0; c2 < C; ++c2) {
    float w = Wo[(size_t)c2 * C + tid];
    #pragma unroll
    for (int r = 0; r < 32; ++r) acc[r] += as[r][c2] * w;
  }
  float bb = bo[tid];
  #pragma unroll
  for (int r = 0; r < 32; ++r) {
    size_t i = (size_t)(rbase + r) * C + tid;
    x2[i] = x[i] + acc[r] + bb;
  }
}

// ------- MLP up: ff = relu(h2 @ W1 + b1) -------
__global__ __launch_bounds__(256) void mlp1_kernel(const float* __restrict__ h2,
    const float* __restrict__ W1, const float* __restrict__ b1,
    float* __restrict__ ff) {
  __shared__ float hsh[32][C];
  int rbase = blockIdx.x * 32;
  int col = blockIdx.y * 256 + threadIdx.x;
  int tid = threadIdx.x;
  for (int idx = tid; idx < 32 * C; idx += 256) {
    int r = idx / C, c = idx % C;
    hsh[r][c] = h2[(size_t)(rbase + r) * C + c];
  }
  __syncthreads();
  float acc[32];
  #pragma unroll
  for (int r = 0; r < 32; ++r) acc[r] = 0.f;
  for (int c = 0; c < C; ++c) {
    float w = W1[(size_t)c * DFF + col];
    #pragma unroll
    for (int r = 0; r < 32; ++r) acc[r] += hsh[r][c] * w;
  }
  float bb = b1[col];
  #pragma unroll
  for (int r = 0; r < 32; ++r) {
    ff[(size_t)(rbase + r) * DFF + col] = fmaxf(acc[r] + bb, 0.f);
  }
}

// ------- MLP down + residual: out = x2 + ff @ W2 + b2 -------
__global__ __launch_bounds__(384) void mlp2_kernel(const float* __restrict__ ff,
    const float* __restrict__ W2, const float* __restrict__ b2,
    const float* __restrict__ x2, float* __restrict__ out) {
  __shared__ float fsh[32][384];
  int rbase = blockIdx.x * 32;
  int tid = threadIdx.x;  // output col
  float acc[32];
  #pragma unroll
  for (int r = 0; r < 32; ++r) acc[r] = 0.f;
  for (int ch = 0; ch < DFF; ch += 384) {
    for (int idx = tid; idx < 32 * 384; idx += 384) {
      int r = idx / 384, c = idx % 384;
      fsh[r][c] = ff[(size_t)(rbase + r) * DFF + ch + c];
    }
    __syncthreads();
    for (int c = 0; c < 384; ++c) {
      float w = W2[(size_t)(ch + c) * C + tid];
      #pragma unroll
      for (int r = 0; r < 32; ++r) acc[r] += fsh[r][c] * w;
    }
    __syncthreads();
  }
  float bb = b2[tid];
  #pragma unroll
  for (int r = 0; r < 32; ++r) {
    size_t i = (size_t)(rbase + r) * C + tid;
    out[i] = x2[i] + acc[r] + bb;
  }
}

extern "C" void kernel_launch(void* const* d_in, const int* in_sizes, int n_in,
                              void* d_out, int out_size, void* d_ws, size_t ws_size,
                              hipStream_t stream) {
  const float* x   = (const float*)d_in[0];
  const float* Wq  = (const float*)d_in[1];
  const float* Wk  = (const float*)d_in[2];
  const float* Wv  = (const float*)d_in[3];
  const float* Wo  = (const float*)d_in[4];
  const float* bo  = (const float*)d_in[5];
  const float* W1  = (const float*)d_in[6];
  const float* b1  = (const float*)d_in[7];
  const float* W2  = (const float*)d_in[8];
  const float* b2  = (const float*)d_in[9];
  const float* g1  = (const float*)d_in[10];
  const float* be1 = (const float*)d_in[11];
  const float* g2  = (const float*)d_in[12];
  const float* be2 = (const float*)d_in[13];
  float* out = (float*)d_out;
  float* ws = (float*)d_ws;

  const size_t S = (size_t)BT * C;  // 6,291,456 floats
  float* hbuf = ws;            // LN output (h1, then h2)
  float* qb   = ws + S;
  float* kb   = ws + 2 * S;
  float* vb   = ws + 3 * S;
  float* ab   = ws + 4 * S;    // attention output [B,T,C]
  float* x2   = ws + 5 * S;    // post-attention residual
  float* ffb  = ws + S;        // reuse q/k/v/attn region: BT*DFF = 4*S

  ln_kernel<<<BT, 64, 0, stream>>>(x, g1, be1, hbuf);
  qkv_kernel<<<dim3(B * H, T / 32), 256, 0, stream>>>(hbuf, Wq, Wk, Wv, qb, kb, vb);
  attn_kernel<<<dim3(B * H, T / 32), 256, 0, stream>>>(qb, kb, vb, ab);
  proj_kernel<<<BT / 32, 384, 0, stream>>>(ab, Wo, bo, x, x2);
  ln_kernel<<<BT, 64, 0, stream>>>(x2, g2, be2, hbuf);
  mlp1_kernel<<<dim3(BT / 32, DFF / 256), 256, 0, stream>>>(hbuf, W1, b1, ffb);
  mlp2_kernel<<<BT / 32, 384, 0, stream>>>(ffb, W2, b2, x2, out);
}

// Round 2
// 404.104 us; speedup vs baseline: 5.5494x; 5.5494x over previous
//
#include <hip/hip_runtime.h>

#define B 64
#define T 256
#define C 384
#define H 6
#define HS 64
#define DFF 1536
#define BT (B*T)

typedef __attribute__((ext_vector_type(8))) short short8;
typedef __attribute__((ext_vector_type(4))) float float4v;

static __device__ __forceinline__ unsigned short f2bf(float f) {
  unsigned int u = __float_as_uint(f);
  unsigned int r = (u + 0x7fffu + ((u >> 16) & 1u)) >> 16;
  return (unsigned short)r;
}

// ---------------- weight prep: transpose + f32->bf16 ----------------
// dst layouts: wqkv[1152][384], wo[384][384], w1t[1536][384], w2t[384][1536]
__global__ __launch_bounds__(256) void prep_w(
    const float* __restrict__ Wq, const float* __restrict__ Wk, const float* __restrict__ Wv,
    const float* __restrict__ Wo, const float* __restrict__ W1, const float* __restrict__ W2,
    unsigned short* __restrict__ wqkv, unsigned short* __restrict__ wo,
    unsigned short* __restrict__ w1t, unsigned short* __restrict__ w2t) {
  __shared__ float tile[32][33];
  int bx = blockIdx.x;
  int x = threadIdx.x & 31, y = threadIdx.x >> 5;
  if (bx < 432) {  // QKV: per head, transpose [384][64] -> wqkv rows
    int tn = bx % 36, tc = bx / 36;        // 36 col-tiles (1152/32), 12 row-tiles (384/32)
    int n0 = tn * 32, c0 = tc * 32;
    int mat = n0 / 384, rem = n0 % 384, head = rem / 64, hs0 = rem % 64;
    const float* W = (mat == 0) ? Wq : ((mat == 1) ? Wk : Wv);
    const float* src = W + (size_t)head * C * HS + hs0;  // src[c][x] at src[c*64 + x]
    #pragma unroll
    for (int i = 0; i < 4; ++i) tile[y + 8 * i][x] = src[(size_t)(c0 + y + 8 * i) * 64 + x];
    __syncthreads();
    #pragma unroll
    for (int i = 0; i < 4; ++i)
      wqkv[(size_t)(n0 + y + 8 * i) * 384 + c0 + x] = f2bf(tile[x][y + 8 * i]);
    return;
  }
  const float* src; unsigned short* dst; int CN, R, n0, c0;
  if (bx < 576) {         // Wo [384][384]
    int t = bx - 432; n0 = (t % 12) * 32; c0 = (t / 12) * 32;
    src = Wo; dst = wo; CN = 384; R = 384;
  } else if (bx < 1152) { // W1 [384][1536]
    int t = bx - 576; n0 = (t % 48) * 32; c0 = (t / 48) * 32;
    src = W1; dst = w1t; CN = 1536; R = 384;
  } else {                // W2 [1536][384]
    int t = bx - 1152; n0 = (t % 12) * 32; c0 = (t / 12) * 32;
    src = W2; dst = w2t; CN = 384; R = 1536;
  }
  #pragma unroll
  for (int i = 0; i < 4; ++i) tile[y + 8 * i][x] = src[(size_t)(c0 + y + 8 * i) * CN + n0 + x];
  __syncthreads();
  #pragma unroll
  for (int i = 0; i < 4; ++i)
    dst[(size_t)(n0 + y + 8 * i) * R + c0 + x] = f2bf(tile[x][y + 8 * i]);
}

// ---------------- LayerNorm: one wave per token, bf16 out ----------------
__global__ __launch_bounds__(64) void ln_kernel(const float* __restrict__ x,
    const float* __restrict__ g, const float* __restrict__ bta,
    unsigned short* __restrict__ out) {
  int t = blockIdx.x;
  int lane = threadIdx.x;
  const float* row = x + (size_t)t * C;
  float v[6];
  float s = 0.f, ss = 0.f;
  #pragma unroll
  for (int i = 0; i < 6; ++i) {
    v[i] = row[lane + i * 64];
    s += v[i];
    ss += v[i] * v[i];
  }
  #pragma unroll
  for (int m = 32; m >= 1; m >>= 1) {
    s += __shfl_xor(s, m);
    ss += __shfl_xor(ss, m);
  }
  float mu = s / C;
  float var = ss / C - mu * mu;
  float rstd = rsqrtf(var + 1e-5f);
  unsigned short* orow = out + (size_t)t * C;
  #pragma unroll
  for (int i = 0; i < 6; ++i) {
    int c = lane + i * 64;
    orow[c] = f2bf((v[i] - mu) * rstd * g[c] + bta[c]);
  }
}

// ---------------- MFMA GEMM: [16384 x K] bf16 @ Wt[N][K] bf16 ----------------
// block 256 thr = 4 waves (2x2), tile 128x64, BK=32; wave computes 64x32 (4x2 frags)
// EPI: 0=qkv scatter f32 (outf=q,outf2=k,outf3=v)  1=proj(+resid+bias->f32)
//      2=mlp1(+bias,relu->bf16)  3=mlp2(+resid+bias->f32)
template<int EPI>
__global__ __launch_bounds__(256) void gemm_kernel(
    const unsigned short* __restrict__ A, const unsigned short* __restrict__ Wt,
    const float* __restrict__ bias, const float* __restrict__ resid,
    float* __restrict__ outf, float* __restrict__ outf2, float* __restrict__ outf3,
    unsigned short* __restrict__ outb, int K, int N) {
  __shared__ unsigned short Ash[128][40];
  __shared__ unsigned short Bsh[64][40];
  int m0 = blockIdx.x * 128;
  int n0 = blockIdx.y * 64;
  int tid = threadIdx.x;
  int lane = tid & 63, wid = tid >> 6;
  int wm = wid >> 1, wn = wid & 1;
  float4v acc[4][2] = {};
  int frow = lane & 15, fk = (lane >> 4) << 3;
  for (int k0 = 0; k0 < K; k0 += 32) {
    __syncthreads();
    #pragma unroll
    for (int i = 0; i < 2; ++i) {
      int idx = tid + i * 256;
      int r = idx >> 2, kk = (idx & 3) << 3;
      *(uint4*)&Ash[r][kk] = *(const uint4*)&A[(size_t)(m0 + r) * K + k0 + kk];
    }
    {
      int r = tid >> 2, kk = (tid & 3) << 3;
      *(uint4*)&Bsh[r][kk] = *(const uint4*)&Wt[(size_t)(n0 + r) * K + k0 + kk];
    }
    __syncthreads();
    short8 af[4], bf[2];
    #pragma unroll
    for (int mi = 0; mi < 4; ++mi) af[mi] = *(short8*)&Ash[wm * 64 + mi * 16 + frow][fk];
    #pragma unroll
    for (int ni = 0; ni < 2; ++ni) bf[ni] = *(short8*)&Bsh[wn * 32 + ni * 16 + frow][fk];
    #pragma unroll
    for (int mi = 0; mi < 4; ++mi)
      #pragma unroll
      for (int ni = 0; ni < 2; ++ni)
        acc[mi][ni] = __builtin_amdgcn_mfma_f32_16x16x32_bf16(af[mi], bf[ni], acc[mi][ni], 0, 0, 0);
  }
  int cl = lane & 15, cg = lane >> 4;
  #pragma unroll
  for (int mi = 0; mi < 4; ++mi) {
    #pragma unroll
    for (int ni = 0; ni < 2; ++ni) {
      #pragma unroll
      for (int j = 0; j < 4; ++j) {
        int gr = m0 + wm * 64 + mi * 16 + cg * 4 + j;
        int gc = n0 + wn * 32 + ni * 16 + cl;
        float val = acc[mi][ni][j];
        if constexpr (EPI == 0) {
          int mat = n0 / 384;
          int head = (n0 % 384) / 64;
          int hs = gc & 63;
          int b = gr >> 8, tt = gr & 255;
          float* dest = (mat == 0) ? outf : ((mat == 1) ? outf2 : outf3);
          dest[(((size_t)(b * H + head)) * T + tt) * HS + hs] = val;
        } else if constexpr (EPI == 1) {
          size_t i = (size_t)gr * N + gc;
          outf[i] = resid[i] + val + bias[gc];
        } else if constexpr (EPI == 2) {
          outb[(size_t)gr * N + gc] = f2bf(fmaxf(val + bias[gc], 0.f));
        } else {
          size_t i = (size_t)gr * N + gc;
          outf[i] = resid[i] + val + bias[gc];
        }
      }
    }
  }
}

// ------- attention: block = (b,h, 32-query tile); scores in LDS, f32 -------
__global__ __launch_bounds__(256) void attn_kernel(const float* __restrict__ q,
    const float* __restrict__ k, const float* __restrict__ v,
    unsigned short* __restrict__ attn) {
  __shared__ float sc[32][T + 1];      // scores, padded
  __shared__ float tile[64][HS + 1];   // K then V tiles
  __shared__ float qs[32][HS + 1];
  int bh = blockIdx.x;
  int b = bh / H, hh = bh % H;
  int qbase = blockIdx.y * 32;
  int tid = threadIdx.x;
  const float scale = 0.125f;  // 1/sqrt(64)
  const float* qptr = q + ((size_t)bh * T) * HS;
  const float* kptr = k + ((size_t)bh * T) * HS;
  const float* vptr = v + ((size_t)bh * T) * HS;
  for (int idx = tid; idx < 32 * HS; idx += 256) {
    int r = idx / HS, c = idx % HS;
    qs[r][c] = qptr[(size_t)(qbase + r) * HS + c];
  }
  int smax = qbase + 32;
  // phase 1: scores
  for (int st = 0; st < smax; st += 64) {
    for (int idx = tid; idx < 64 * HS; idx += 256) {
      int r = idx / HS, c = idx % HS;
      tile[r][c] = kptr[(size_t)(st + r) * HS + c];
    }
    __syncthreads();
    #pragma unroll
    for (int i = 0; i < 8; ++i) {
      int idx = i * 256 + tid;
      int ql = idx / 64, s = idx % 64;
      int tq = qbase + ql;
      int sg = st + s;
      float d;
      if (sg > tq) {
        d = -1e30f;
      } else {
        d = 0.f;
        #pragma unroll
        for (int c = 0; c < HS; ++c) d += qs[ql][c] * tile[s][c];
        d *= scale;
      }
      sc[ql][sg] = d;
    }
    __syncthreads();
  }
  // phase 2: wave-parallel softmax, 8 lanes per row
  {
    int r = tid >> 3, g = tid & 7;
    int tq = qbase + r;
    float m = -1e30f;
    for (int s = g; s <= tq; s += 8) m = fmaxf(m, sc[r][s]);
    #pragma unroll
    for (int off = 4; off; off >>= 1) m = fmaxf(m, __shfl_xor(m, off, 8));
    float l = 0.f;
    for (int s = g; s <= tq; s += 8) { float e = __expf(sc[r][s] - m); sc[r][s] = e; l += e; }
    #pragma unroll
    for (int off = 4; off; off >>= 1) l += __shfl_xor(l, off, 8);
    float inv = 1.f / l;
    for (int s = g; s <= tq; s += 8) sc[r][s] *= inv;
    for (int s = tq + 1 + g; s < T; s += 8) sc[r][s] = 0.f;
  }
  __syncthreads();
  // phase 3: out = w @ V
  float acc[8];
  #pragma unroll
  for (int i = 0; i < 8; ++i) acc[i] = 0.f;
  for (int st = 0; st < smax; st += 64) {
    for (int idx = tid; idx < 64 * HS; idx += 256) {
      int r = idx / HS, c = idx % HS;
      tile[r][c] = vptr[(size_t)(st + r) * HS + c];
    }
    __syncthreads();
    #pragma unroll
    for (int i = 0; i < 8; ++i) {
      int idx = i * 256 + tid;
      int ql = idx / 64, kk = idx % 64;
      float a = acc[i];
      #pragma unroll
      for (int s = 0; s < 64; ++s) a += sc[ql][st + s] * tile[s][kk];
      acc[i] = a;
    }
    __syncthreads();
  }
  #pragma unroll
  for (int i = 0; i < 8; ++i) {
    int idx = i * 256 + tid;
    int ql = idx / 64, kk = idx % 64;
    int t = qbase + ql;
    attn[(((size_t)(b * T + t)) * H + hh) * HS + kk] = f2bf(acc[i]);
  }
}

extern "C" void kernel_launch(void* const* d_in, const int* in_sizes, int n_in,
                              void* d_out, int out_size, void* d_ws, size_t ws_size,
                              hipStream_t stream) {
  const float* x   = (const float*)d_in[0];
  const float* Wq  = (const float*)d_in[1];
  const float* Wk  = (const float*)d_in[2];
  const float* Wv  = (const float*)d_in[3];
  const float* Wo  = (const float*)d_in[4];
  const float* bo  = (const float*)d_in[5];
  const float* W1  = (const float*)d_in[6];
  const float* b1  = (const float*)d_in[7];
  const float* W2  = (const float*)d_in[8];
  const float* b2  = (const float*)d_in[9];
  const float* g1  = (const float*)d_in[10];
  const float* be1 = (const float*)d_in[11];
  const float* g2  = (const float*)d_in[12];
  const float* be2 = (const float*)d_in[13];
  float* out = (float*)d_out;
  float* ws = (float*)d_ws;

  // workspace layout (float units)
  unsigned short* wqkv_t = (unsigned short*)ws;          // 442368 shorts
  unsigned short* wo_t   = wqkv_t + 442368;              // 147456
  unsigned short* w1t    = wo_t + 147456;                // 589824
  unsigned short* w2t    = w1t + 589824;                 // 589824  (total 884736 floats)
  float* base2 = ws + 884736;
  unsigned short* h  = (unsigned short*)base2;           // 3145728 floats
  float* x2 = base2 + 3145728;                           // 6291456 floats
  unsigned short* ab = (unsigned short*)(x2 + 6291456);  // 3145728 floats
  float* qb = x2 + 6291456 + 3145728;                    // 6291456
  float* kb = qb + 6291456;                              // 6291456
  float* vb = kb + 6291456;                              // 6291456
  unsigned short* ffb = (unsigned short*)qb;             // reuses q+k (25.2MB bf16)

  prep_w<<<1728, 256, 0, stream>>>(Wq, Wk, Wv, Wo, W1, W2, wqkv_t, wo_t, w1t, w2t);
  ln_kernel<<<BT, 64, 0, stream>>>(x, g1, be1, h);
  gemm_kernel<0><<<dim3(128, 18), 256, 0, stream>>>(h, wqkv_t, nullptr, nullptr,
                                                    qb, kb, vb, nullptr, 384, 1152);
  attn_kernel<<<dim3(B * H, T / 32), 256, 0, stream>>>(qb, kb, vb, ab);
  gemm_kernel<1><<<dim3(128, 6), 256, 0, stream>>>(ab, wo_t, bo, x,
                                                   x2, nullptr, nullptr, nullptr, 384, 384);
  ln_kernel<<<BT, 64, 0, stream>>>(x2, g2, be2, h);
  gemm_kernel<2><<<dim3(128, 24), 256, 0, stream>>>(h, w1t, b1, nullptr,
                                                    nullptr, nullptr, nullptr, ffb, 384, 1536);
  gemm_kernel<3><<<dim3(128, 6), 256, 0, stream>>>(ffb, w2t, b2, x2,
                                                   out, nullptr, nullptr, nullptr, 1536, 384);
}

// Round 3
// 179.684 us; speedup vs baseline: 12.4804x; 2.2490x over previous
//
#include <hip/hip_runtime.h>

#define B 64
#define T 256
#define C 384
#define H 6
#define HS 64
#define DFF 1536
#define BT (B*T)

typedef __attribute__((ext_vector_type(8))) short short8;
typedef __attribute__((ext_vector_type(4))) float float4v;
typedef __attribute__((ext_vector_type(4))) unsigned short ushort4v;

static __device__ __forceinline__ unsigned short f2bf(float f) {
  unsigned int u = __float_as_uint(f);
  unsigned int r = (u + 0x7fffu + ((u >> 16) & 1u)) >> 16;
  return (unsigned short)r;
}

// ---------------- weight prep: transpose + f32->bf16 ----------------
__global__ __launch_bounds__(256) void prep_w(
    const float* __restrict__ Wq, const float* __restrict__ Wk, const float* __restrict__ Wv,
    const float* __restrict__ Wo, const float* __restrict__ W1, const float* __restrict__ W2,
    unsigned short* __restrict__ wqkv, unsigned short* __restrict__ wo,
    unsigned short* __restrict__ w1t, unsigned short* __restrict__ w2t) {
  __shared__ float tile[32][33];
  int bx = blockIdx.x;
  int x = threadIdx.x & 31, y = threadIdx.x >> 5;
  if (bx < 432) {  // QKV -> wqkv[1152][384]
    int tn = bx % 36, tc = bx / 36;
    int n0 = tn * 32, c0 = tc * 32;
    int mat = n0 / 384, rem = n0 % 384, head = rem / 64, hs0 = rem % 64;
    const float* W = (mat == 0) ? Wq : ((mat == 1) ? Wk : Wv);
    const float* src = W + (size_t)head * C * HS + hs0;
    #pragma unroll
    for (int i = 0; i < 4; ++i) tile[y + 8 * i][x] = src[(size_t)(c0 + y + 8 * i) * 64 + x];
    __syncthreads();
    #pragma unroll
    for (int i = 0; i < 4; ++i)
      wqkv[(size_t)(n0 + y + 8 * i) * 384 + c0 + x] = f2bf(tile[x][y + 8 * i]);
    return;
  }
  const float* src; unsigned short* dst; int CN, R, n0, c0;
  if (bx < 576) {         // Wo [384][384]
    int t = bx - 432; n0 = (t % 12) * 32; c0 = (t / 12) * 32;
    src = Wo; dst = wo; CN = 384; R = 384;
  } else if (bx < 1152) { // W1 [384][1536]
    int t = bx - 576; n0 = (t % 48) * 32; c0 = (t / 48) * 32;
    src = W1; dst = w1t; CN = 1536; R = 384;
  } else {                // W2 [1536][384]
    int t = bx - 1152; n0 = (t % 12) * 32; c0 = (t / 12) * 32;
    src = W2; dst = w2t; CN = 384; R = 1536;
  }
  #pragma unroll
  for (int i = 0; i < 4; ++i) tile[y + 8 * i][x] = src[(size_t)(c0 + y + 8 * i) * CN + n0 + x];
  __syncthreads();
  #pragma unroll
  for (int i = 0; i < 4; ++i)
    dst[(size_t)(n0 + y + 8 * i) * R + c0 + x] = f2bf(tile[x][y + 8 * i]);
}

// ---------------- LayerNorm: one wave per token, bf16 out ----------------
__global__ __launch_bounds__(64) void ln_kernel(const float* __restrict__ x,
    const float* __restrict__ g, const float* __restrict__ bta,
    unsigned short* __restrict__ out) {
  int t = blockIdx.x;
  int lane = threadIdx.x;
  const float* row = x + (size_t)t * C;
  float v[6];
  float s = 0.f, ss = 0.f;
  #pragma unroll
  for (int i = 0; i < 6; ++i) {
    v[i] = row[lane + i * 64];
    s += v[i];
    ss += v[i] * v[i];
  }
  #pragma unroll
  for (int m = 32; m >= 1; m >>= 1) {
    s += __shfl_xor(s, m);
    ss += __shfl_xor(ss, m);
  }
  float mu = s / C;
  float var = ss / C - mu * mu;
  float rstd = rsqrtf(var + 1e-5f);
  unsigned short* orow = out + (size_t)t * C;
  #pragma unroll
  for (int i = 0; i < 6; ++i) {
    int c = lane + i * 64;
    orow[c] = f2bf((v[i] - mu) * rstd * g[c] + bta[c]);
  }
}

// ---------------- MFMA GEMM: [16384 x K] bf16 @ Wt[N][K] bf16 ----------------
// EPI: 0=qkv scatter bf16 (outb=q, outb2=k, outb3=v^T)
//      1=proj(+resid+bias->f32)  2=mlp1(+bias,relu->bf16)  3=mlp2(+resid+bias->f32)
template<int EPI>
__global__ __launch_bounds__(256) void gemm_kernel(
    const unsigned short* __restrict__ A, const unsigned short* __restrict__ Wt,
    const float* __restrict__ bias, const float* __restrict__ resid,
    float* __restrict__ outf,
    unsigned short* __restrict__ outb, unsigned short* __restrict__ outb2,
    unsigned short* __restrict__ outb3, int K, int N) {
  __shared__ unsigned short Ash[128][40];
  __shared__ unsigned short Bsh[64][40];
  int m0 = blockIdx.x * 128;
  int n0 = blockIdx.y * 64;
  int tid = threadIdx.x;
  int lane = tid & 63, wid = tid >> 6;
  int wm = wid >> 1, wn = wid & 1;
  float4v acc[4][2] = {};
  int frow = lane & 15, fk = (lane >> 4) << 3;
  for (int k0 = 0; k0 < K; k0 += 32) {
    __syncthreads();
    #pragma unroll
    for (int i = 0; i < 2; ++i) {
      int idx = tid + i * 256;
      int r = idx >> 2, kk = (idx & 3) << 3;
      *(uint4*)&Ash[r][kk] = *(const uint4*)&A[(size_t)(m0 + r) * K + k0 + kk];
    }
    {
      int r = tid >> 2, kk = (tid & 3) << 3;
      *(uint4*)&Bsh[r][kk] = *(const uint4*)&Wt[(size_t)(n0 + r) * K + k0 + kk];
    }
    __syncthreads();
    short8 af[4], bf[2];
    #pragma unroll
    for (int mi = 0; mi < 4; ++mi) af[mi] = *(short8*)&Ash[wm * 64 + mi * 16 + frow][fk];
    #pragma unroll
    for (int ni = 0; ni < 2; ++ni) bf[ni] = *(short8*)&Bsh[wn * 32 + ni * 16 + frow][fk];
    #pragma unroll
    for (int mi = 0; mi < 4; ++mi)
      #pragma unroll
      for (int ni = 0; ni < 2; ++ni)
        acc[mi][ni] = __builtin_amdgcn_mfma_f32_16x16x32_bf16(af[mi], bf[ni], acc[mi][ni], 0, 0, 0);
  }
  int cl = lane & 15, cg = lane >> 4;
  #pragma unroll
  for (int mi = 0; mi < 4; ++mi) {
    #pragma unroll
    for (int ni = 0; ni < 2; ++ni) {
      if constexpr (EPI == 0) {
        int mat = n0 / 384;
        int head = (n0 >> 6) % 6;
        int hs = wn * 32 + ni * 16 + cl;
        int gr0 = m0 + wm * 64 + mi * 16 + cg * 4;
        int tt0 = gr0 & 255, bidx = gr0 >> 8;
        size_t bhb = (size_t)(bidx * H + head);
        if (mat == 2) {
          ushort4v pk;
          #pragma unroll
          for (int j = 0; j < 4; ++j) pk[j] = f2bf(acc[mi][ni][j]);
          *(ushort4v*)&outb3[(bhb * HS + hs) * T + tt0] = pk;
        } else {
          unsigned short* dst = (mat == 0) ? outb : outb2;
          #pragma unroll
          for (int j = 0; j < 4; ++j)
            dst[(bhb * T + tt0 + j) * HS + hs] = f2bf(acc[mi][ni][j]);
        }
      } else {
        #pragma unroll
        for (int j = 0; j < 4; ++j) {
          int gr = m0 + wm * 64 + mi * 16 + cg * 4 + j;
          int gc = n0 + wn * 32 + ni * 16 + cl;
          float val = acc[mi][ni][j];
          if constexpr (EPI == 1) {
            size_t i = (size_t)gr * N + gc;
            outf[i] = resid[i] + val + bias[gc];
          } else if constexpr (EPI == 2) {
            outb[(size_t)gr * N + gc] = f2bf(fmaxf(val + bias[gc], 0.f));
          } else {
            size_t i = (size_t)gr * N + gc;
            outf[i] = resid[i] + val + bias[gc];
          }
        }
      }
    }
  }
}

// ------- MFMA attention: block = (b,h, 64-query tile), 4 waves -------
// q,k: bf16 [bh][t][hs]; v: bf16 [bh][hs][t] (pre-transposed)
__global__ __launch_bounds__(256) void attn_kernel(
    const unsigned short* __restrict__ qg, const unsigned short* __restrict__ kg,
    const unsigned short* __restrict__ vtg, unsigned short* __restrict__ ab) {
  __shared__ unsigned short Ksh[64 * 64];    // [s][hs], XOR-swizzled
  __shared__ unsigned short Vsh[64 * 256];   // [hs][s], XOR-swizzled
  __shared__ unsigned short Psh[4 * 16 * 256];  // per-wave [16 q][256 s], swizzled
  int bh = blockIdx.x;
  int bb = bh / H, hh = bh % H;
  int qt = blockIdx.y, q0 = qt * 64;
  int tid = threadIdx.x, lane = tid & 63, w = tid >> 6;
  int cl = lane & 15, cg = lane >> 4;
  const float scale_log2e = 0.125f * 1.44269504f;
  const unsigned short* qp = qg + ((size_t)bh * T) * HS;
  const unsigned short* kp = kg + ((size_t)bh * T) * HS;
  const unsigned short* vp = vtg + ((size_t)bh * HS) * T;

  // Q fragments (rows q0+w*16+cl, k-slices)
  short8 aq[2];
  #pragma unroll
  for (int k0 = 0; k0 < 2; ++k0)
    aq[k0] = *(const short8*)&qp[(size_t)(q0 + w * 16 + cl) * HS + cg * 8 + k0 * 32];

  // stage V^T [64][256] swizzled (covered by K-loop barriers)
  #pragma unroll
  for (int i = 0; i < 8; ++i) {
    int idx = tid + i * 256;
    int r = idx >> 5, c16 = idx & 31;
    uint4 val = *(const uint4*)&vp[(size_t)r * T + c16 * 8];
    int byte = (r * 512 + c16 * 16) ^ ((r & 7) << 4);
    *(uint4*)((char*)Vsh + byte) = val;
  }

  // ---- scores: S[16][256] per wave, in C/D frag layout ----
  float4v sacc[4][4] = {};
  for (int si = 0; si <= qt; ++si) {
    __syncthreads();
    #pragma unroll
    for (int i = 0; i < 2; ++i) {
      int idx = tid + i * 256;
      int r = idx >> 3, c16 = idx & 7;
      uint4 val = *(const uint4*)&kp[(size_t)(si * 64 + r) * HS + c16 * 8];
      int byte = (r * 128 + c16 * 16) ^ ((r & 7) << 4);
      *(uint4*)((char*)Ksh + byte) = val;
    }
    __syncthreads();
    #pragma unroll
    for (int ss = 0; ss < 4; ++ss) {  // static accumulator index (rule #20)
      if (ss == si) {
        #pragma unroll
        for (int nt = 0; nt < 4; ++nt) {
          int srow = nt * 16 + cl;
          #pragma unroll
          for (int k0 = 0; k0 < 2; ++k0) {
            int byte = (srow * 128 + (cg * 8 + k0 * 32) * 2) ^ ((srow & 7) << 4);
            short8 bf = *(const short8*)((char*)Ksh + byte);
            sacc[ss][nt] = __builtin_amdgcn_mfma_f32_16x16x32_bf16(aq[k0], bf, sacc[ss][nt], 0, 0, 0);
          }
        }
      }
    }
  }

  // ---- causal mask on last tile ----
  #pragma unroll
  for (int si = 0; si < 4; ++si) {
    if (si == qt) {
      #pragma unroll
      for (int nt = 0; nt < 4; ++nt) {
        int s = q0 + nt * 16 + cl;
        #pragma unroll
        for (int j = 0; j < 4; ++j) {
          int q = q0 + w * 16 + cg * 4 + j;
          if (s > q) sacc[si][nt][j] = -1e30f;
        }
      }
    }
  }

  // ---- in-register softmax (rows owned by (cg,j); reduce across 16-lane col group) ----
  float lj[4];
  #pragma unroll
  for (int j = 0; j < 4; ++j) {
    float m = -1e30f;
    #pragma unroll
    for (int si = 0; si < 4; ++si) if (si <= qt)
      #pragma unroll
      for (int nt = 0; nt < 4; ++nt) m = fmaxf(m, sacc[si][nt][j]);
    #pragma unroll
    for (int off = 1; off < 16; off <<= 1) m = fmaxf(m, __shfl_xor(m, off));
    float l = 0.f;
    #pragma unroll
    for (int si = 0; si < 4; ++si) if (si <= qt)
      #pragma unroll
      for (int nt = 0; nt < 4; ++nt) {
        float p0 = exp2f((sacc[si][nt][0 ? 0 : j] - m) * scale_log2e);
        sacc[si][nt][j] = p0;
        l += p0;
      }
    #pragma unroll
    for (int off = 1; off < 16; off <<= 1) l += __shfl_xor(l, off);
    lj[j] = 1.f / l;
  }

  // ---- P -> bf16 -> per-wave LDS (swizzled) ----
  char* pbase = (char*)Psh + w * 8192;
  #pragma unroll
  for (int si = 0; si < 4; ++si) if (si <= qt)
    #pragma unroll
    for (int nt = 0; nt < 4; ++nt)
      #pragma unroll
      for (int j = 0; j < 4; ++j) {
        int prow = cg * 4 + j, col = si * 64 + nt * 16 + cl;
        int byte = (prow * 512 + col * 2) ^ ((prow & 7) << 4);
        *(unsigned short*)(pbase + byte) = f2bf(sacc[si][nt][j]);
      }

  // ---- O = P @ V ----
  int nks = 2 * (qt + 1);
  #pragma unroll
  for (int nt = 0; nt < 4; ++nt) {
    float4v oacc = {};
    for (int ks = 0; ks < nks; ++ks) {
      int k = ks * 32 + cg * 8;
      int pbyte = (cl * 512 + k * 2) ^ ((cl & 7) << 4);
      short8 af = *(const short8*)(pbase + pbyte);
      int vr = nt * 16 + cl;
      int vbyte = (vr * 512 + k * 2) ^ ((vr & 7) << 4);
      short8 bf = *(const short8*)((char*)Vsh + vbyte);
      oacc = __builtin_amdgcn_mfma_f32_16x16x32_bf16(af, bf, oacc, 0, 0, 0);
    }
    #pragma unroll
    for (int j = 0; j < 4; ++j) {
      int t = q0 + w * 16 + cg * 4 + j;
      ab[((size_t)(bb * T + t)) * C + hh * 64 + nt * 16 + cl] = f2bf(oacc[j] * lj[j]);
    }
  }
}

extern "C" void kernel_launch(void* const* d_in, const int* in_sizes, int n_in,
                              void* d_out, int out_size, void* d_ws, size_t ws_size,
                              hipStream_t stream) {
  const float* x   = (const float*)d_in[0];
  const float* Wq  = (const float*)d_in[1];
  const float* Wk  = (const float*)d_in[2];
  const float* Wv  = (const float*)d_in[3];
  const float* Wo  = (const float*)d_in[4];
  const float* bo  = (const float*)d_in[5];
  const float* W1  = (const float*)d_in[6];
  const float* b1  = (const float*)d_in[7];
  const float* W2  = (const float*)d_in[8];
  const float* b2  = (const float*)d_in[9];
  const float* g1  = (const float*)d_in[10];
  const float* be1 = (const float*)d_in[11];
  const float* g2  = (const float*)d_in[12];
  const float* be2 = (const float*)d_in[13];
  float* out = (float*)d_out;
  float* ws = (float*)d_ws;

  // workspace layout (float units)
  unsigned short* wqkv_t = (unsigned short*)ws;          // 442368 sh = 221184 fl
  unsigned short* wo_t   = wqkv_t + 442368;              // 147456 sh
  unsigned short* w1t    = wo_t + 147456;                // 589824 sh
  unsigned short* w2t    = w1t + 589824;                 // 589824 sh (tot 884736 fl)
  float* base2 = ws + 884736;
  unsigned short* h  = (unsigned short*)base2;           // 3145728 fl
  float* x2 = base2 + 3145728;                           // 6291456 fl
  unsigned short* ab = (unsigned short*)(x2 + 6291456);  // 3145728 fl
  unsigned short* qb = (unsigned short*)(x2 + 6291456 + 3145728);      // 3145728 fl
  unsigned short* kb = qb + 6291456;                     // 3145728 fl
  unsigned short* vt = kb + 6291456;                     // 3145728 fl
  unsigned short* ffb = ab;                              // reuses ab+qb+kb+vt (12.58M fl)

  prep_w<<<1728, 256, 0, stream>>>(Wq, Wk, Wv, Wo, W1, W2, wqkv_t, wo_t, w1t, w2t);
  ln_kernel<<<BT, 64, 0, stream>>>(x, g1, be1, h);
  gemm_kernel<0><<<dim3(128, 18), 256, 0, stream>>>(h, wqkv_t, nullptr, nullptr,
                                                    nullptr, qb, kb, vt, 384, 1152);
  attn_kernel<<<dim3(B * H, T / 64), 256, 0, stream>>>(qb, kb, vt, ab);
  gemm_kernel<1><<<dim3(128, 6), 256, 0, stream>>>(ab, wo_t, bo, x,
                                                   x2, nullptr, nullptr, nullptr, 384, 384);
  ln_kernel<<<BT, 64, 0, stream>>>(x2, g2, be2, h);
  gemm_kernel<2><<<dim3(128, 24), 256, 0, stream>>>(h, w1t, b1, nullptr,
                                                    nullptr, ffb, nullptr, nullptr, 384, 1536);
  gemm_kernel<3><<<dim3(128, 6), 256, 0, stream>>>(ffb, w2t, b2, x2,
                                                   out, nullptr, nullptr, nullptr, 1536, 384);
}

// Round 4
// 161.860 us; speedup vs baseline: 13.8548x; 1.1101x over previous
//
#include <hip/hip_runtime.h>

#define B 64
#define T 256
#define C 384
#define H 6
#define HS 64
#define DFF 1536
#define BT (B*T)

typedef __attribute__((ext_vector_type(8))) short short8;
typedef __attribute__((ext_vector_type(4))) float float4v;
typedef __attribute__((ext_vector_type(4))) unsigned short ushort4v;

static __device__ __forceinline__ unsigned short f2bf(float f) {
  unsigned int u = __float_as_uint(f);
  unsigned int r = (u + 0x7fffu + ((u >> 16) & 1u)) >> 16;
  return (unsigned short)r;
}

typedef __attribute__((address_space(1))) const unsigned int ga_u32;
typedef __attribute__((address_space(3))) unsigned int ls_u32;
static __device__ __forceinline__ void gld16(const void* g, void* l) {
  __builtin_amdgcn_global_load_lds((ga_u32*)g, (ls_u32*)l, 16, 0, 0);
}

// ---------------- weight prep: transpose + f32->bf16 ----------------
__global__ __launch_bounds__(256) void prep_w(
    const float* __restrict__ Wq, const float* __restrict__ Wk, const float* __restrict__ Wv,
    const float* __restrict__ Wo, const float* __restrict__ W1, const float* __restrict__ W2,
    unsigned short* __restrict__ wqkv, unsigned short* __restrict__ wo,
    unsigned short* __restrict__ w1t, unsigned short* __restrict__ w2t) {
  __shared__ float tile[32][33];
  int bx = blockIdx.x;
  int x = threadIdx.x & 31, y = threadIdx.x >> 5;
  if (bx < 432) {  // QKV -> wqkv[1152][384]
    int tn = bx % 36, tc = bx / 36;
    int n0 = tn * 32, c0 = tc * 32;
    int mat = n0 / 384, rem = n0 % 384, head = rem / 64, hs0 = rem % 64;
    const float* W = (mat == 0) ? Wq : ((mat == 1) ? Wk : Wv);
    const float* src = W + (size_t)head * C * HS + hs0;
    #pragma unroll
    for (int i = 0; i < 4; ++i) tile[y + 8 * i][x] = src[(size_t)(c0 + y + 8 * i) * 64 + x];
    __syncthreads();
    #pragma unroll
    for (int i = 0; i < 4; ++i)
      wqkv[(size_t)(n0 + y + 8 * i) * 384 + c0 + x] = f2bf(tile[x][y + 8 * i]);
    return;
  }
  const float* src; unsigned short* dst; int CN, R, n0, c0;
  if (bx < 576) {         // Wo [384][384]
    int t = bx - 432; n0 = (t % 12) * 32; c0 = (t / 12) * 32;
    src = Wo; dst = wo; CN = 384; R = 384;
  } else if (bx < 1152) { // W1 [384][1536]
    int t = bx - 576; n0 = (t % 48) * 32; c0 = (t / 48) * 32;
    src = W1; dst = w1t; CN = 1536; R = 384;
  } else {                // W2 [1536][384]
    int t = bx - 1152; n0 = (t % 12) * 32; c0 = (t / 12) * 32;
    src = W2; dst = w2t; CN = 384; R = 1536;
  }
  #pragma unroll
  for (int i = 0; i < 4; ++i) tile[y + 8 * i][x] = src[(size_t)(c0 + y + 8 * i) * CN + n0 + x];
  __syncthreads();
  #pragma unroll
  for (int i = 0; i < 4; ++i)
    dst[(size_t)(n0 + y + 8 * i) * R + c0 + x] = f2bf(tile[x][y + 8 * i]);
}

// ---------------- LayerNorm: one wave per token, bf16 out ----------------
__global__ __launch_bounds__(64) void ln_kernel(const float* __restrict__ x,
    const float* __restrict__ g, const float* __restrict__ bta,
    unsigned short* __restrict__ out) {
  int t = blockIdx.x;
  int lane = threadIdx.x;
  const float* row = x + (size_t)t * C;
  float v[6];
  float s = 0.f, ss = 0.f;
  #pragma unroll
  for (int i = 0; i < 6; ++i) {
    v[i] = row[lane + i * 64];
    s += v[i];
    ss += v[i] * v[i];
  }
  #pragma unroll
  for (int m = 32; m >= 1; m >>= 1) {
    s += __shfl_xor(s, m);
    ss += __shfl_xor(ss, m);
  }
  float mu = s / C;
  float var = ss / C - mu * mu;
  float rstd = rsqrtf(var + 1e-5f);
  unsigned short* orow = out + (size_t)t * C;
  #pragma unroll
  for (int i = 0; i < 6; ++i) {
    int c = lane + i * 64;
    orow[c] = f2bf((v[i] - mu) * rstd * g[c] + bta[c]);
  }
}

// ------------- m97-style MFMA GEMM: A[16384 x K] @ Wt[N][K], tile MTx128 -------------
// BK=64; LDS linear (global_load_lds dest), XOR-swizzle via pre-swizzled global src
// + swizzled ds_read (rule #21: source-perm == read-perm involution).
// EPI: 0=qkv scatter bf16 (outb=q, outb2=k, outb3=v^T)
//      1=proj(+resid+bias->f32)  2=mlp1(+bias,relu->bf16)  3=mlp2(+resid+bias->f32)
template<int EPI, int MT>
__global__ __launch_bounds__(MT * 2) void gemm_kernel(
    const unsigned short* __restrict__ A, const unsigned short* __restrict__ Wt,
    const float* __restrict__ bias, const float* __restrict__ resid,
    float* __restrict__ outf,
    unsigned short* __restrict__ outb, unsigned short* __restrict__ outb2,
    unsigned short* __restrict__ outb3, int K, int N) {
  __shared__ unsigned short Ash[MT * 64];   // [MT rows][64 k] bf16, 128B rows
  __shared__ unsigned short Bsh[128 * 64];  // [128 n-rows][64 k]
  constexpr int NW = MT / 32;   // waves (4 or 2)
  constexpr int NA = 4;         // A 1KB-chunks per wave
  constexpr int NB = 16 / NW;   // B 1KB-chunks per wave
  int tid = threadIdx.x, lane = tid & 63, w = tid >> 6;
  int wm, wn;
  if constexpr (MT == 128) { wm = w >> 1; wn = w & 1; } else { wm = 0; wn = w; }
  int m0 = blockIdx.x * MT, n0 = blockIdx.y * 128;
  int lrow = lane >> 3;                    // row within 8-row chunk
  int lchunk = (lane & 7) ^ (lrow & 7);    // pre-swizzled global 16B-chunk
  int frow = lane & 15, cg = lane >> 4;
  float4v acc[4][4] = {};
  for (int k0 = 0; k0 < K; k0 += 64) {
    __syncthreads();
    #pragma unroll
    for (int i = 0; i < NA; ++i)
      gld16(A + (size_t)(m0 + w * (NA * 8) + i * 8 + lrow) * K + k0 + lchunk * 8,
            &Ash[(w * NA + i) * 512]);
    #pragma unroll
    for (int i = 0; i < NB; ++i)
      gld16(Wt + (size_t)(n0 + w * (NB * 8) + i * 8 + lrow) * K + k0 + lchunk * 8,
            &Bsh[(w * NB + i) * 512]);
    __syncthreads();
    #pragma unroll
    for (int ks = 0; ks < 2; ++ks) {
      short8 af[4], bf[4];
      #pragma unroll
      for (int mi = 0; mi < 4; ++mi) {
        int r = wm * 64 + mi * 16 + frow;
        int ch = (ks * 4 + cg) ^ (r & 7);
        af[mi] = *(const short8*)((const char*)Ash + r * 128 + ch * 16);
      }
      #pragma unroll
      for (int ni = 0; ni < 4; ++ni) {
        int r = wn * 64 + ni * 16 + frow;
        int ch = (ks * 4 + cg) ^ (r & 7);
        bf[ni] = *(const short8*)((const char*)Bsh + r * 128 + ch * 16);
      }
      #pragma unroll
      for (int mi = 0; mi < 4; ++mi)
        #pragma unroll
        for (int ni = 0; ni < 4; ++ni)
          acc[mi][ni] = __builtin_amdgcn_mfma_f32_16x16x32_bf16(af[mi], bf[ni], acc[mi][ni], 0, 0, 0);
    }
  }
  int cl = lane & 15;
  #pragma unroll
  for (int mi = 0; mi < 4; ++mi) {
    #pragma unroll
    for (int ni = 0; ni < 4; ++ni) {
      if constexpr (EPI == 0) {
        int gc = n0 + wn * 64 + ni * 16 + cl;
        int mat = gc / 384;
        int head = (gc % 384) >> 6;
        int hs = gc & 63;
        int gr0 = m0 + wm * 64 + mi * 16 + cg * 4;
        int tt0 = gr0 & 255, bidx = gr0 >> 8;
        size_t bhb = (size_t)(bidx * H + head);
        if (mat == 2) {
          ushort4v pk;
          #pragma unroll
          for (int j = 0; j < 4; ++j) pk[j] = f2bf(acc[mi][ni][j]);
          *(ushort4v*)&outb3[(bhb * HS + hs) * T + tt0] = pk;
        } else {
          unsigned short* dst = (mat == 0) ? outb : outb2;
          #pragma unroll
          for (int j = 0; j < 4; ++j)
            dst[(bhb * T + tt0 + j) * HS + hs] = f2bf(acc[mi][ni][j]);
        }
      } else {
        #pragma unroll
        for (int j = 0; j < 4; ++j) {
          int gr = m0 + wm * 64 + mi * 16 + cg * 4 + j;
          int gc = n0 + wn * 64 + ni * 16 + cl;
          float val = acc[mi][ni][j];
          if constexpr (EPI == 1) {
            size_t i = (size_t)gr * N + gc;
            outf[i] = resid[i] + val + bias[gc];
          } else if constexpr (EPI == 2) {
            outb[(size_t)gr * N + gc] = f2bf(fmaxf(val + bias[gc], 0.f));
          } else {
            size_t i = (size_t)gr * N + gc;
            outf[i] = resid[i] + val + bias[gc];
          }
        }
      }
    }
  }
}

// ------- MFMA attention: block = (b,h, 64-query tile), 4 waves -------
// q,k: bf16 [bh][t][hs]; v: bf16 [bh][hs][t] (pre-transposed)
__global__ __launch_bounds__(256) void attn_kernel(
    const unsigned short* __restrict__ qg, const unsigned short* __restrict__ kg,
    const unsigned short* __restrict__ vtg, unsigned short* __restrict__ ab) {
  __shared__ unsigned short Ksh[64 * 64];    // [s][hs], XOR-swizzled
  __shared__ unsigned short Vsh[64 * 256];   // [hs][s], XOR-swizzled
  __shared__ unsigned short Psh[4 * 16 * 256];  // per-wave [16 q][256 s], swizzled
  int bh = blockIdx.x;
  int bb = bh / H, hh = bh % H;
  int qt = blockIdx.y, q0 = qt * 64;
  int tid = threadIdx.x, lane = tid & 63, w = tid >> 6;
  int cl = lane & 15, cg = lane >> 4;
  const float scale_log2e = 0.125f * 1.44269504f;
  const unsigned short* qp = qg + ((size_t)bh * T) * HS;
  const unsigned short* kp = kg + ((size_t)bh * T) * HS;
  const unsigned short* vp = vtg + ((size_t)bh * HS) * T;

  short8 aq[2];
  #pragma unroll
  for (int k0 = 0; k0 < 2; ++k0)
    aq[k0] = *(const short8*)&qp[(size_t)(q0 + w * 16 + cl) * HS + cg * 8 + k0 * 32];

  #pragma unroll
  for (int i = 0; i < 8; ++i) {
    int idx = tid + i * 256;
    int r = idx >> 5, c16 = idx & 31;
    uint4 val = *(const uint4*)&vp[(size_t)r * T + c16 * 8];
    int byte = (r * 512 + c16 * 16) ^ ((r & 7) << 4);
    *(uint4*)((char*)Vsh + byte) = val;
  }

  float4v sacc[4][4] = {};
  for (int si = 0; si <= qt; ++si) {
    __syncthreads();
    #pragma unroll
    for (int i = 0; i < 2; ++i) {
      int idx = tid + i * 256;
      int r = idx >> 3, c16 = idx & 7;
      uint4 val = *(const uint4*)&kp[(size_t)(si * 64 + r) * HS + c16 * 8];
      int byte = (r * 128 + c16 * 16) ^ ((r & 7) << 4);
      *(uint4*)((char*)Ksh + byte) = val;
    }
    __syncthreads();
    #pragma unroll
    for (int ss = 0; ss < 4; ++ss) {
      if (ss == si) {
        #pragma unroll
        for (int nt = 0; nt < 4; ++nt) {
          int srow = nt * 16 + cl;
          #pragma unroll
          for (int k0 = 0; k0 < 2; ++k0) {
            int byte = (srow * 128 + (cg * 8 + k0 * 32) * 2) ^ ((srow & 7) << 4);
            short8 bf = *(const short8*)((char*)Ksh + byte);
            sacc[ss][nt] = __builtin_amdgcn_mfma_f32_16x16x32_bf16(aq[k0], bf, sacc[ss][nt], 0, 0, 0);
          }
        }
      }
    }
  }

  #pragma unroll
  for (int si = 0; si < 4; ++si) {
    if (si == qt) {
      #pragma unroll
      for (int nt = 0; nt < 4; ++nt) {
        int s = q0 + nt * 16 + cl;
        #pragma unroll
        for (int j = 0; j < 4; ++j) {
          int q = q0 + w * 16 + cg * 4 + j;
          if (s > q) sacc[si][nt][j] = -1e30f;
        }
      }
    }
  }

  float lj[4];
  #pragma unroll
  for (int j = 0; j < 4; ++j) {
    float m = -1e30f;
    #pragma unroll
    for (int si = 0; si < 4; ++si) if (si <= qt)
      #pragma unroll
      for (int nt = 0; nt < 4; ++nt) m = fmaxf(m, sacc[si][nt][j]);
    #pragma unroll
    for (int off = 1; off < 16; off <<= 1) m = fmaxf(m, __shfl_xor(m, off));
    float l = 0.f;
    #pragma unroll
    for (int si = 0; si < 4; ++si) if (si <= qt)
      #pragma unroll
      for (int nt = 0; nt < 4; ++nt) {
        float p0 = exp2f((sacc[si][nt][j] - m) * scale_log2e);
        sacc[si][nt][j] = p0;
        l += p0;
      }
    #pragma unroll
    for (int off = 1; off < 16; off <<= 1) l += __shfl_xor(l, off);
    lj[j] = 1.f / l;
  }

  char* pbase = (char*)Psh + w * 8192;
  #pragma unroll
  for (int si = 0; si < 4; ++si) if (si <= qt)
    #pragma unroll
    for (int nt = 0; nt < 4; ++nt)
      #pragma unroll
      for (int j = 0; j < 4; ++j) {
        int prow = cg * 4 + j, col = si * 64 + nt * 16 + cl;
        int byte = (prow * 512 + col * 2) ^ ((prow & 7) << 4);
        *(unsigned short*)(pbase + byte) = f2bf(sacc[si][nt][j]);
      }

  int nks = 2 * (qt + 1);
  #pragma unroll
  for (int nt = 0; nt < 4; ++nt) {
    float4v oacc = {};
    for (int ks = 0; ks < nks; ++ks) {
      int k = ks * 32 + cg * 8;
      int pbyte = (cl * 512 + k * 2) ^ ((cl & 7) << 4);
      short8 af = *(const short8*)(pbase + pbyte);
      int vr = nt * 16 + cl;
      int vbyte = (vr * 512 + k * 2) ^ ((vr & 7) << 4);
      short8 bf = *(const short8*)((char*)Vsh + vbyte);
      oacc = __builtin_amdgcn_mfma_f32_16x16x32_bf16(af, bf, oacc, 0, 0, 0);
    }
    #pragma unroll
    for (int j = 0; j < 4; ++j) {
      int t = q0 + w * 16 + cg * 4 + j;
      ab[((size_t)(bb * T + t)) * C + hh * 64 + nt * 16 + cl] = f2bf(oacc[j] * lj[j]);
    }
  }
}

extern "C" void kernel_launch(void* const* d_in, const int* in_sizes, int n_in,
                              void* d_out, int out_size, void* d_ws, size_t ws_size,
                              hipStream_t stream) {
  const float* x   = (const float*)d_in[0];
  const float* Wq  = (const float*)d_in[1];
  const float* Wk  = (const float*)d_in[2];
  const float* Wv  = (const float*)d_in[3];
  const float* Wo  = (const float*)d_in[4];
  const float* bo  = (const float*)d_in[5];
  const float* W1  = (const float*)d_in[6];
  const float* b1  = (const float*)d_in[7];
  const float* W2  = (const float*)d_in[8];
  const float* b2  = (const float*)d_in[9];
  const float* g1  = (const float*)d_in[10];
  const float* be1 = (const float*)d_in[11];
  const float* g2  = (const float*)d_in[12];
  const float* be2 = (const float*)d_in[13];
  float* out = (float*)d_out;
  float* ws = (float*)d_ws;

  // workspace layout (float units)
  unsigned short* wqkv_t = (unsigned short*)ws;          // 442368 sh
  unsigned short* wo_t   = wqkv_t + 442368;              // 147456 sh
  unsigned short* w1t    = wo_t + 147456;                // 589824 sh
  unsigned short* w2t    = w1t + 589824;                 // 589824 sh (tot 884736 fl)
  float* base2 = ws + 884736;
  unsigned short* h  = (unsigned short*)base2;           // 3145728 fl
  float* x2 = base2 + 3145728;                           // 6291456 fl
  unsigned short* ab = (unsigned short*)(x2 + 6291456);  // 3145728 fl
  unsigned short* qb = (unsigned short*)(x2 + 6291456 + 3145728);      // 3145728 fl
  unsigned short* kb = qb + 6291456;                     // 3145728 fl
  unsigned short* vt = kb + 6291456;                     // 3145728 fl
  unsigned short* ffb = ab;                              // reuses ab.. (12.58M fl)

  prep_w<<<1728, 256, 0, stream>>>(Wq, Wk, Wv, Wo, W1, W2, wqkv_t, wo_t, w1t, w2t);
  ln_kernel<<<BT, 64, 0, stream>>>(x, g1, be1, h);
  gemm_kernel<0, 128><<<dim3(128, 9), 256, 0, stream>>>(h, wqkv_t, nullptr, nullptr,
                                                        nullptr, qb, kb, vt, 384, 1152);
  attn_kernel<<<dim3(B * H, T / 64), 256, 0, stream>>>(qb, kb, vt, ab);
  gemm_kernel<1, 64><<<dim3(256, 3), 128, 0, stream>>>(ab, wo_t, bo, x,
                                                       x2, nullptr, nullptr, nullptr, 384, 384);
  ln_kernel<<<BT, 64, 0, stream>>>(x2, g2, be2, h);
  gemm_kernel<2, 128><<<dim3(128, 12), 256, 0, stream>>>(h, w1t, b1, nullptr,
                                                         nullptr, ffb, nullptr, nullptr, 384, 1536);
  gemm_kernel<3, 64><<<dim3(256, 3), 128, 0, stream>>>(ffb, w2t, b2, x2,
                                                       out, nullptr, nullptr, nullptr, 1536, 384);
}

// Round 5
// 153.912 us; speedup vs baseline: 14.5702x; 1.0516x over previous
//
#include <hip/hip_runtime.h>

#define B 64
#define T 256
#define C 384
#define H 6
#define HS 64
#define DFF 1536
#define BT (B*T)

typedef __attribute__((ext_vector_type(8))) short short8;
typedef __attribute__((ext_vector_type(4))) float float4v;
typedef __attribute__((ext_vector_type(4))) unsigned short ushort4v;

static __device__ __forceinline__ unsigned short f2bf(float f) {
  unsigned int u = __float_as_uint(f);
  unsigned int r = (u + 0x7fffu + ((u >> 16) & 1u)) >> 16;
  return (unsigned short)r;
}

typedef __attribute__((address_space(1))) const unsigned int ga_u32;
typedef __attribute__((address_space(3))) unsigned int ls_u32;
static __device__ __forceinline__ void gld16(const void* g, void* l) {
  __builtin_amdgcn_global_load_lds((ga_u32*)g, (ls_u32*)l, 16, 0, 0);
}

// ---------------- weight prep: transpose + f32->bf16 ----------------
__global__ __launch_bounds__(256) void prep_w(
    const float* __restrict__ Wq, const float* __restrict__ Wk, const float* __restrict__ Wv,
    const float* __restrict__ Wo, const float* __restrict__ W1, const float* __restrict__ W2,
    unsigned short* __restrict__ wqkv, unsigned short* __restrict__ wo,
    unsigned short* __restrict__ w1t, unsigned short* __restrict__ w2t) {
  __shared__ float tile[32][33];
  int bx = blockIdx.x;
  int x = threadIdx.x & 31, y = threadIdx.x >> 5;
  if (bx < 432) {  // QKV -> wqkv[1152][384]
    int tn = bx % 36, tc = bx / 36;
    int n0 = tn * 32, c0 = tc * 32;
    int mat = n0 / 384, rem = n0 % 384, head = rem / 64, hs0 = rem % 64;
    const float* W = (mat == 0) ? Wq : ((mat == 1) ? Wk : Wv);
    const float* src = W + (size_t)head * C * HS + hs0;
    #pragma unroll
    for (int i = 0; i < 4; ++i) tile[y + 8 * i][x] = src[(size_t)(c0 + y + 8 * i) * 64 + x];
    __syncthreads();
    #pragma unroll
    for (int i = 0; i < 4; ++i)
      wqkv[(size_t)(n0 + y + 8 * i) * 384 + c0 + x] = f2bf(tile[x][y + 8 * i]);
    return;
  }
  const float* src; unsigned short* dst; int CN, R, n0, c0;
  if (bx < 576) {         // Wo [384][384]
    int t = bx - 432; n0 = (t % 12) * 32; c0 = (t / 12) * 32;
    src = Wo; dst = wo; CN = 384; R = 384;
  } else if (bx < 1152) { // W1 [384][1536]
    int t = bx - 576; n0 = (t % 48) * 32; c0 = (t / 48) * 32;
    src = W1; dst = w1t; CN = 1536; R = 384;
  } else {                // W2 [1536][384]
    int t = bx - 1152; n0 = (t % 12) * 32; c0 = (t / 12) * 32;
    src = W2; dst = w2t; CN = 384; R = 1536;
  }
  #pragma unroll
  for (int i = 0; i < 4; ++i) tile[y + 8 * i][x] = src[(size_t)(c0 + y + 8 * i) * CN + n0 + x];
  __syncthreads();
  #pragma unroll
  for (int i = 0; i < 4; ++i)
    dst[(size_t)(n0 + y + 8 * i) * R + c0 + x] = f2bf(tile[x][y + 8 * i]);
}

// ---------------- LayerNorm: one wave per token, bf16 out ----------------
__global__ __launch_bounds__(64) void ln_kernel(const float* __restrict__ x,
    const float* __restrict__ g, const float* __restrict__ bta,
    unsigned short* __restrict__ out) {
  int t = blockIdx.x;
  int lane = threadIdx.x;
  const float* row = x + (size_t)t * C;
  float v[6];
  float s = 0.f, ss = 0.f;
  #pragma unroll
  for (int i = 0; i < 6; ++i) {
    v[i] = row[lane + i * 64];
    s += v[i];
    ss += v[i] * v[i];
  }
  #pragma unroll
  for (int m = 32; m >= 1; m >>= 1) {
    s += __shfl_xor(s, m);
    ss += __shfl_xor(ss, m);
  }
  float mu = s / C;
  float var = ss / C - mu * mu;
  float rstd = rsqrtf(var + 1e-5f);
  unsigned short* orow = out + (size_t)t * C;
  #pragma unroll
  for (int i = 0; i < 6; ++i) {
    int c = lane + i * 64;
    orow[c] = f2bf((v[i] - mu) * rstd * g[c] + bta[c]);
  }
}

// ------------- m97-style MFMA GEMM: A[16384 x K] @ Wt[N][K], tile MTx128 -------------
// 256 threads = 4 waves (2x2); wave tile (MT/2)x64; BK=64.
// LDS linear (global_load_lds dest); XOR-swizzle via pre-swizzled global src
// + swizzled ds_read (rule #21: source-perm == read-perm involution).
// EPI: 0=qkv scatter bf16 (outb=q, outb2=k, outb3=v^T)
//      1=proj(+resid+bias->f32)  2=mlp1(+bias,relu->bf16)  3=mlp2(+resid+bias->f32)
template<int EPI, int MT>
__global__ __launch_bounds__(256) void gemm_kernel(
    const unsigned short* __restrict__ A, const unsigned short* __restrict__ Wt,
    const float* __restrict__ bias, const float* __restrict__ resid,
    float* __restrict__ outf,
    unsigned short* __restrict__ outb, unsigned short* __restrict__ outb2,
    unsigned short* __restrict__ outb3, int K, int N) {
  __shared__ unsigned short Ash[MT * 64];   // [MT rows][64 k] bf16, 128B rows
  __shared__ unsigned short Bsh[128 * 64];  // [128 n-rows][64 k]
  constexpr int MR = MT / 32;   // M-frags per wave (4 or 2)
  constexpr int NA = MT / 32;   // A 1KB-chunks per wave
  int tid = threadIdx.x, lane = tid & 63, w = tid >> 6;
  int wm = w >> 1, wn = w & 1;
  int m0 = blockIdx.x * MT, n0 = blockIdx.y * 128;
  int lrow = lane >> 3;                    // row within 8-row chunk
  int lchunk = (lane & 7) ^ (lrow & 7);    // pre-swizzled global 16B-chunk
  int frow = lane & 15, cg = lane >> 4;
  float4v acc[MR][4] = {};
  for (int k0 = 0; k0 < K; k0 += 64) {
    __syncthreads();
    #pragma unroll
    for (int i = 0; i < NA; ++i)
      gld16(A + (size_t)(m0 + w * (NA * 8) + i * 8 + lrow) * K + k0 + lchunk * 8,
            &Ash[(w * NA + i) * 512]);
    #pragma unroll
    for (int i = 0; i < 4; ++i)
      gld16(Wt + (size_t)(n0 + w * 32 + i * 8 + lrow) * K + k0 + lchunk * 8,
            &Bsh[(w * 4 + i) * 512]);
    __syncthreads();
    #pragma unroll
    for (int ks = 0; ks < 2; ++ks) {
      short8 af[MR], bf[4];
      #pragma unroll
      for (int mi = 0; mi < MR; ++mi) {
        int r = wm * (MR * 16) + mi * 16 + frow;
        int ch = (ks * 4 + cg) ^ (r & 7);
        af[mi] = *(const short8*)((const char*)Ash + r * 128 + ch * 16);
      }
      #pragma unroll
      for (int ni = 0; ni < 4; ++ni) {
        int r = wn * 64 + ni * 16 + frow;
        int ch = (ks * 4 + cg) ^ (r & 7);
        bf[ni] = *(const short8*)((const char*)Bsh + r * 128 + ch * 16);
      }
      #pragma unroll
      for (int mi = 0; mi < MR; ++mi)
        #pragma unroll
        for (int ni = 0; ni < 4; ++ni)
          acc[mi][ni] = __builtin_amdgcn_mfma_f32_16x16x32_bf16(af[mi], bf[ni], acc[mi][ni], 0, 0, 0);
    }
  }
  int cl = lane & 15;
  #pragma unroll
  for (int mi = 0; mi < MR; ++mi) {
    #pragma unroll
    for (int ni = 0; ni < 4; ++ni) {
      if constexpr (EPI == 0) {
        int gc = n0 + wn * 64 + ni * 16 + cl;
        int mat = gc / 384;
        int head = (gc % 384) >> 6;
        int hs = gc & 63;
        int gr0 = m0 + wm * (MR * 16) + mi * 16 + cg * 4;
        int tt0 = gr0 & 255, bidx = gr0 >> 8;
        size_t bhb = (size_t)(bidx * H + head);
        if (mat == 2) {
          ushort4v pk;
          #pragma unroll
          for (int j = 0; j < 4; ++j) pk[j] = f2bf(acc[mi][ni][j]);
          *(ushort4v*)&outb3[(bhb * HS + hs) * T + tt0] = pk;
        } else {
          unsigned short* dst = (mat == 0) ? outb : outb2;
          #pragma unroll
          for (int j = 0; j < 4; ++j)
            dst[(bhb * T + tt0 + j) * HS + hs] = f2bf(acc[mi][ni][j]);
        }
      } else {
        #pragma unroll
        for (int j = 0; j < 4; ++j) {
          int gr = m0 + wm * (MR * 16) + mi * 16 + cg * 4 + j;
          int gc = n0 + wn * 64 + ni * 16 + cl;
          float val = acc[mi][ni][j];
          if constexpr (EPI == 1) {
            size_t i = (size_t)gr * N + gc;
            outf[i] = resid[i] + val + bias[gc];
          } else if constexpr (EPI == 2) {
            outb[(size_t)gr * N + gc] = f2bf(fmaxf(val + bias[gc], 0.f));
          } else {
            size_t i = (size_t)gr * N + gc;
            outf[i] = resid[i] + val + bias[gc];
          }
        }
      }
    }
  }
}

// ------- MFMA attention: block = (b,h, 64-query tile), 4 waves -------
// q,k: bf16 [bh][t][hs]; v: bf16 [bh][hs][t] (pre-transposed)
__global__ __launch_bounds__(256) void attn_kernel(
    const unsigned short* __restrict__ qg, const unsigned short* __restrict__ kg,
    const unsigned short* __restrict__ vtg, unsigned short* __restrict__ ab) {
  __shared__ unsigned short Ksh[64 * 64];    // [s][hs], XOR-swizzled
  __shared__ unsigned short Vsh[64 * 256];   // [hs][s], XOR-swizzled
  __shared__ unsigned short Psh[4 * 16 * 256];  // per-wave [16 q][256 s], swizzled
  int bh = blockIdx.x;
  int bb = bh / H, hh = bh % H;
  int qt = blockIdx.y, q0 = qt * 64;
  int tid = threadIdx.x, lane = tid & 63, w = tid >> 6;
  int cl = lane & 15, cg = lane >> 4;
  const float scale_log2e = 0.125f * 1.44269504f;
  const unsigned short* qp = qg + ((size_t)bh * T) * HS;
  const unsigned short* kp = kg + ((size_t)bh * T) * HS;
  const unsigned short* vp = vtg + ((size_t)bh * HS) * T;

  short8 aq[2];
  #pragma unroll
  for (int k0 = 0; k0 < 2; ++k0)
    aq[k0] = *(const short8*)&qp[(size_t)(q0 + w * 16 + cl) * HS + cg * 8 + k0 * 32];

  #pragma unroll
  for (int i = 0; i < 8; ++i) {
    int idx = tid + i * 256;
    int r = idx >> 5, c16 = idx & 31;
    uint4 val = *(const uint4*)&vp[(size_t)r * T + c16 * 8];
    int byte = (r * 512 + c16 * 16) ^ ((r & 7) << 4);
    *(uint4*)((char*)Vsh + byte) = val;
  }

  float4v sacc[4][4] = {};
  for (int si = 0; si <= qt; ++si) {
    __syncthreads();
    #pragma unroll
    for (int i = 0; i < 2; ++i) {
      int idx = tid + i * 256;
      int r = idx >> 3, c16 = idx & 7;
      uint4 val = *(const uint4*)&kp[(size_t)(si * 64 + r) * HS + c16 * 8];
      int byte = (r * 128 + c16 * 16) ^ ((r & 7) << 4);
      *(uint4*)((char*)Ksh + byte) = val;
    }
    __syncthreads();
    #pragma unroll
    for (int ss = 0; ss < 4; ++ss) {
      if (ss == si) {
        #pragma unroll
        for (int nt = 0; nt < 4; ++nt) {
          int srow = nt * 16 + cl;
          #pragma unroll
          for (int k0 = 0; k0 < 2; ++k0) {
            int byte = (srow * 128 + (cg * 8 + k0 * 32) * 2) ^ ((srow & 7) << 4);
            short8 bf = *(const short8*)((char*)Ksh + byte);
            sacc[ss][nt] = __builtin_amdgcn_mfma_f32_16x16x32_bf16(aq[k0], bf, sacc[ss][nt], 0, 0, 0);
          }
        }
      }
    }
  }

  #pragma unroll
  for (int si = 0; si < 4; ++si) {
    if (si == qt) {
      #pragma unroll
      for (int nt = 0; nt < 4; ++nt) {
        int s = q0 + nt * 16 + cl;
        #pragma unroll
        for (int j = 0; j < 4; ++j) {
          int q = q0 + w * 16 + cg * 4 + j;
          if (s > q) sacc[si][nt][j] = -1e30f;
        }
      }
    }
  }

  float lj[4];
  #pragma unroll
  for (int j = 0; j < 4; ++j) {
    float m = -1e30f;
    #pragma unroll
    for (int si = 0; si < 4; ++si) if (si <= qt)
      #pragma unroll
      for (int nt = 0; nt < 4; ++nt) m = fmaxf(m, sacc[si][nt][j]);
    #pragma unroll
    for (int off = 1; off < 16; off <<= 1) m = fmaxf(m, __shfl_xor(m, off));
    float l = 0.f;
    #pragma unroll
    for (int si = 0; si < 4; ++si) if (si <= qt)
      #pragma unroll
      for (int nt = 0; nt < 4; ++nt) {
        float p0 = exp2f((sacc[si][nt][j] - m) * scale_log2e);
        sacc[si][nt][j] = p0;
        l += p0;
      }
    #pragma unroll
    for (int off = 1; off < 16; off <<= 1) l += __shfl_xor(l, off);
    lj[j] = 1.f / l;
  }

  char* pbase = (char*)Psh + w * 8192;
  #pragma unroll
  for (int si = 0; si < 4; ++si) if (si <= qt)
    #pragma unroll
    for (int nt = 0; nt < 4; ++nt)
      #pragma unroll
      for (int j = 0; j < 4; ++j) {
        int prow = cg * 4 + j, col = si * 64 + nt * 16 + cl;
        int byte = (prow * 512 + col * 2) ^ ((prow & 7) << 4);
        *(unsigned short*)(pbase + byte) = f2bf(sacc[si][nt][j]);
      }

  int nks = 2 * (qt + 1);
  #pragma unroll
  for (int nt = 0; nt < 4; ++nt) {
    float4v oacc = {};
    for (int ks = 0; ks < nks; ++ks) {
      int k = ks * 32 + cg * 8;
      int pbyte = (cl * 512 + k * 2) ^ ((cl & 7) << 4);
      short8 af = *(const short8*)(pbase + pbyte);
      int vr = nt * 16 + cl;
      int vbyte = (vr * 512 + k * 2) ^ ((vr & 7) << 4);
      short8 bf = *(const short8*)((char*)Vsh + vbyte);
      oacc = __builtin_amdgcn_mfma_f32_16x16x32_bf16(af, bf, oacc, 0, 0, 0);
    }
    #pragma unroll
    for (int j = 0; j < 4; ++j) {
      int t = q0 + w * 16 + cg * 4 + j;
      ab[((size_t)(bb * T + t)) * C + hh * 64 + nt * 16 + cl] = f2bf(oacc[j] * lj[j]);
    }
  }
}

extern "C" void kernel_launch(void* const* d_in, const int* in_sizes, int n_in,
                              void* d_out, int out_size, void* d_ws, size_t ws_size,
                              hipStream_t stream) {
  const float* x   = (const float*)d_in[0];
  const float* Wq  = (const float*)d_in[1];
  const float* Wk  = (const float*)d_in[2];
  const float* Wv  = (const float*)d_in[3];
  const float* Wo  = (const float*)d_in[4];
  const float* bo  = (const float*)d_in[5];
  const float* W1  = (const float*)d_in[6];
  const float* b1  = (const float*)d_in[7];
  const float* W2  = (const float*)d_in[8];
  const float* b2  = (const float*)d_in[9];
  const float* g1  = (const float*)d_in[10];
  const float* be1 = (const float*)d_in[11];
  const float* g2  = (const float*)d_in[12];
  const float* be2 = (const float*)d_in[13];
  float* out = (float*)d_out;
  float* ws = (float*)d_ws;

  // workspace layout (float units)
  unsigned short* wqkv_t = (unsigned short*)ws;          // 442368 sh
  unsigned short* wo_t   = wqkv_t + 442368;              // 147456 sh
  unsigned short* w1t    = wo_t + 147456;                // 589824 sh
  unsigned short* w2t    = w1t + 589824;                 // 589824 sh (tot 884736 fl)
  float* base2 = ws + 884736;
  unsigned short* h  = (unsigned short*)base2;           // 3145728 fl
  float* x2 = base2 + 3145728;                           // 6291456 fl
  unsigned short* ab = (unsigned short*)(x2 + 6291456);  // 3145728 fl
  unsigned short* qb = (unsigned short*)(x2 + 6291456 + 3145728);      // 3145728 fl
  unsigned short* kb = qb + 6291456;                     // 3145728 fl
  unsigned short* vt = kb + 6291456;                     // 3145728 fl
  unsigned short* ffb = ab;                              // reuses ab.. (12.58M fl)

  prep_w<<<1728, 256, 0, stream>>>(Wq, Wk, Wv, Wo, W1, W2, wqkv_t, wo_t, w1t, w2t);
  ln_kernel<<<BT, 64, 0, stream>>>(x, g1, be1, h);
  gemm_kernel<0, 128><<<dim3(128, 9), 256, 0, stream>>>(h, wqkv_t, nullptr, nullptr,
                                                        nullptr, qb, kb, vt, 384, 1152);
  attn_kernel<<<dim3(B * H, T / 64), 256, 0, stream>>>(qb, kb, vt, ab);
  gemm_kernel<1, 64><<<dim3(256, 3), 256, 0, stream>>>(ab, wo_t, bo, x,
                                                       x2, nullptr, nullptr, nullptr, 384, 384);
  ln_kernel<<<BT, 64, 0, stream>>>(x2, g2, be2, h);
  gemm_kernel<2, 128><<<dim3(128, 12), 256, 0, stream>>>(h, w1t, b1, nullptr,
                                                         nullptr, ffb, nullptr, nullptr, 384, 1536);
  gemm_kernel<3, 64><<<dim3(256, 3), 256, 0, stream>>>(ffb, w2t, b2, x2,
                                                       out, nullptr, nullptr, nullptr, 1536, 384);
}